// Round 1
// 102.447 us; speedup vs baseline: 1.0323x; 1.0323x over previous
//
#include <hip/hip_runtime.h>
#include <math.h>

#define S 128
#define H 64
#define RPB 8            // rays per block
#define SPB (RPB * S)    // 1024 samples per block
#define T 256

typedef __attribute__((ext_vector_type(8))) short bf16x8;
typedef __attribute__((ext_vector_type(4))) float f32x4;
#define MFMA16(a, b, c) __builtin_amdgcn_mfma_f32_16x16x32_bf16((a), (b), (c), 0, 0, 0)

// RNE float->bf16: native cast -> v_cvt_pk_bf16_f32 on gfx950 (1 VALU op,
// vs 3-op manual bit-twiddle in rounds 0-9; same RNE result on finite inputs)
__device__ __forceinline__ short f2bf(float x) {
    __bf16 b = (__bf16)x;
    return __builtin_bit_cast(short, b);
}

// ---------------------------------------------------------------------------
// Exact-geometry occupancy mask (identical op sequence since round 0;
// _rn intrinsics forbid fma contraction so floor() cells bit-match numpy).
// ---------------------------------------------------------------------------
__device__ __forceinline__ bool sample_mask(
    float ox, float oy, float oz, float dx, float dy, float dz,
    float nr, float step, int s, const float* __restrict__ density)
{
    const float z  = __fadd_rn(nr, __fmul_rn((float)s, step));
    const float px = __fadd_rn(ox, __fmul_rn(z, dx));
    const float py = __fadd_rn(oy, __fmul_rn(z, dy));
    const float pz = __fadd_rn(oz, __fmul_rn(z, dz));
    const float gx = floorf(__fmul_rn(__fdiv_rn(__fsub_rn(px, -1.25f), 2.5f), 64.0f));
    const float gy = floorf(__fmul_rn(__fdiv_rn(__fsub_rn(py, -1.55f), 2.5f), 64.0f));
    const float gz = floorf(__fmul_rn(__fdiv_rn(__fsub_rn(pz, -1.25f), 2.5f), 64.0f));
    const int ix = (int)gx, iy = (int)gy, iz = (int)gz;
    const bool inb = (ix >= 0) && (ix < 64) && (iy >= 0) && (iy < 64) &&
                     (iz >= 0) && (iz < 64);
    const int cx = min(max(ix, 0), 63);
    const int cy = min(max(iy, 0), 63);
    const int cz = min(max(iz, 0), 63);
    const float dval = density[(cx << 12) | (cy << 6) | cz];
    return inb && (dval > 0.5f);
}

// ---------------------------------------------------------------------------
// Fused kernel, round 10:
//  - f2bf via native __bf16 cast (v_cvt_pk_bf16_f32): -2 VALU per convert.
//  - b1 folded into W1 as K-row 3 (A[m][3]=1.0): kills 16 v_add/task, -4 VGPR.
//  - per-ray {o,d,near,step} staged in LDS: per-task fdiv + 8 global loads
//    -> 2 ds_read_b128.
//  - sW2t (dead after frag build) overlaid with s_r/s_g via union:
//    LDS 36.9 -> ~28.3 KB -> 5 blocks/CU; __launch_bounds__(256,5).
//  - fast-math epilogue (__expf + v_rcp) for alpha/sigmoids.
// MFMA layouts (16x16x32 bf16, HW-verified m89/m91/m120, round-8 end-to-end):
//   A-frag: lane holds A[m=lane&15][k=8*quad+j]; B-frag: B[k=8*quad+j][n=lane&15]
//   C/D: reg r = C[row=4*quad+r][col=lane&15]
// L3 computed swapped (D = W3^T * relu(h2)): quad-0 lanes hold all 4 output
// channels of their sample -> shuffle-free epilogue.
// ---------------------------------------------------------------------------
__global__ __launch_bounds__(256, 5)
void fused_mfma_kernel(const float* __restrict__ rays_o, const float* __restrict__ rays_d,
                       const float* __restrict__ nearv, const float* __restrict__ farv,
                       const float* __restrict__ jitter, const float* __restrict__ density,
                       const float* __restrict__ W1, const float* __restrict__ b1,
                       const float* __restrict__ W2, const float* __restrict__ b2,
                       const float* __restrict__ Wsig, const float* __restrict__ bsig,
                       const float* __restrict__ Wrgb, const float* __restrict__ brgb,
                       float* __restrict__ out, int N)
{
    // sW2t is only read during the once-per-block fragment build; after that
    // its 9.2 KB is reused for s_r/s_g (writes begin only after sync #2).
    __shared__ __align__(16) union {
        short w2t[H * 72];        // bf16 W2 transposed [n][k], 9216 B
        float rg[2 * SPB];        // s_r | s_g, 8192 B
    } s_u;
    __shared__ __align__(16) short hX[4][16 * 72];     // per-wave h1/h2 scratch, 9.2 KB
    __shared__ unsigned short s_list[SPB];             // 2 KB
    __shared__ __align__(16) float s_alpha[SPB];       // 4 KB
    __shared__ __align__(16) float s_bv[SPB];          // 4 KB
    __shared__ __align__(16) float s_ray[RPB][8];      // {ox,oy,oz,dx,dy,dz,nr,step}
    __shared__ int s_wcnt[4];
    __shared__ int s_wbase[4];

    short* const sW2t = s_u.w2t;
    float* const s_r  = s_u.rg;
    float* const s_g  = s_u.rg + SPB;
    float* const s_b  = s_bv;

    const int tid  = threadIdx.x;
    const int lane = tid & 63;
    const int wv   = tid >> 6;
    const int blk  = blockIdx.x;
    const int mrow = lane & 15;      // 16-dim index (row for A/C, col for B)
    const int quad = lane >> 4;      // k-quad

    // ---- stage per-ray data (8 rays) ----
    if (tid < RPB) {
        const int gr = blk * RPB + tid;
        float ox = 0.f, oy = 0.f, oz = 0.f, dx = 0.f, dy = 0.f, dz = 0.f,
              nr = 0.f, st = 0.f;
        if (gr < N) {
            ox = rays_o[gr * 3 + 0]; oy = rays_o[gr * 3 + 1]; oz = rays_o[gr * 3 + 2];
            dx = rays_d[gr * 3 + 0]; dy = rays_d[gr * 3 + 1]; dz = rays_d[gr * 3 + 2];
            nr = nearv[gr];
            st = __fdiv_rn(__fsub_rn(farv[gr], nr), 128.0f);
        }
        s_ray[tid][0] = ox; s_ray[tid][1] = oy; s_ray[tid][2] = oz; s_ray[tid][3] = dx;
        s_ray[tid][4] = dy; s_ray[tid][5] = dz; s_ray[tid][6] = nr; s_ray[tid][7] = st;
    }
    // ---- stage W2 bf16 TRANSPOSED into LDS (coalesced global reads) ----
    for (int e = tid; e < H * H; e += T) {
        const int k = e >> 6, n = e & 63;
        sW2t[n * 72 + k] = f2bf(W2[e]);
    }
    __syncthreads();   // sync 1: s_ray + sW2t visible

    // ================= Phase A: mask (registers only) =======================
    const int lbase = tid * 4;            // local sample ids lbase..lbase+3
    const int rloc  = lbase >> 7;         // local ray 0..7
    const int gra   = blk * RPB + rloc;
    unsigned int mybits = 0u;
    {
        const float4 rv0 = *reinterpret_cast<const float4*>(&s_ray[rloc][0]);
        const float4 rv1 = *reinterpret_cast<const float4*>(&s_ray[rloc][4]);
        if (gra < N) {
            const int s0 = lbase & (S - 1);
            #pragma unroll
            for (int j = 0; j < 4; ++j) {
                if (sample_mask(rv0.x, rv0.y, rv0.z, rv0.w, rv1.x, rv1.y,
                                rv1.z, rv1.w, s0 + j, density))
                    mybits |= (1u << j);
            }
        }
    }
    const int mycnt = __popc(mybits);
    int inc = mycnt;
    #pragma unroll
    for (int off = 1; off < 64; off <<= 1) {
        const int u = __shfl_up(inc, off, 64);
        if (lane >= off) inc += u;
    }
    if (lane == 63) s_wcnt[wv] = inc;

    // ================= Weight fragments (once per block) ====================
    // Built here, between sync 1 and sync 2, so sW2t can be reused afterwards.
    // W2 B-frags: one ds_read_b128 each from the transposed image.
    bf16x8 w2f[4][2];
    #pragma unroll
    for (int nt = 0; nt < 4; ++nt) {
        #pragma unroll
        for (int ks = 0; ks < 2; ++ks) {
            w2f[nt][ks] = *(const bf16x8*)&sW2t[(mrow + 16 * nt) * 72 + 32 * ks + 8 * quad];
        }
    }
    // W1 B-frags: rows k=0..2 = input dims, row k=3 = b1 (A supplies 1.0)
    bf16x8 w1f[4];
    #pragma unroll
    for (int nt = 0; nt < 4; ++nt) {
        bf16x8 f = {0, 0, 0, 0, 0, 0, 0, 0};
        if (quad == 0) {
            const int n = mrow + 16 * nt;
            f[0] = f2bf(W1[n]);
            f[1] = f2bf(W1[64 + n]);
            f[2] = f2bf(W1[128 + n]);
            f[3] = f2bf(b1[n]);          // bias row (exact: b1 == 0 here)
        }
        w1f[nt] = f;
    }
    // L3 A-frags: A[m=channel][k]; ch0=Wsig, ch1..3=Wrgb
    bf16x8 a3f[2];
    #pragma unroll
    for (int ks = 0; ks < 2; ++ks) {
        bf16x8 f = {0, 0, 0, 0, 0, 0, 0, 0};
        if (mrow < 4) {
            #pragma unroll
            for (int j = 0; j < 8; ++j) {
                const int k = 32 * ks + 8 * quad + j;
                const float v = (mrow == 0) ? Wsig[k] : Wrgb[k * 3 + (mrow - 1)];
                f[j] = f2bf(v);
            }
        }
        a3f[ks] = f;
    }
    float b2v[4];
    #pragma unroll
    for (int nt = 0; nt < 4; ++nt) b2v[nt] = b2[mrow + 16 * nt];
    const float bsg = bsig[0];
    const float br0 = brgb[0], br1 = brgb[1], br2 = brgb[2];

    __syncthreads();   // sync 2: s_wcnt visible; all sW2t reads complete
    if (tid == 0) {
        int t0 = 0;
        #pragma unroll
        for (int i = 0; i < 4; ++i) { s_wbase[i] = t0; t0 += s_wcnt[i]; }
    }
    __syncthreads();   // sync 3: s_wbase visible; safe to clobber sW2t region
    int pos = s_wbase[wv] + (inc - mycnt);
    #pragma unroll
    for (int j = 0; j < 4; ++j) {
        if ((mybits >> j) & 1u) {
            s_list[pos++] = (unsigned short)(lbase + j);
        } else {
            s_alpha[lbase + j] = 0.0f;
            s_r[lbase + j] = 0.0f;
            s_g[lbase + j] = 0.0f;
            s_b[lbase + j] = 0.0f;
        }
    }
    const int K = s_wbase[3] + s_wcnt[3];
    __syncthreads();   // sync 4: s_list + zero-fills visible

    // ================= Phase B: MFMA MLP over 16-sample tasks ===============
    const f32x4 z4 = {0.f, 0.f, 0.f, 0.f};
    const int ntask = (K + 15) >> 4;
    short* const hb  = &hX[wv][0];
    short* const hwr = hb + (4 * quad) * 72 + mrow;   // C-store base
    const short* const hrd = hb + mrow * 72 + 8 * quad; // A/B-frag read base

    for (int t = wv; t < ntask; t += 4) {
        const int slot = (t << 4) + mrow;
        const bool valid = slot < K;
        const int id = s_list[valid ? slot : 0];
        const int ri = id >> 7;
        const int s  = id & (S - 1);
        const float4 rv0 = *reinterpret_cast<const float4*>(&s_ray[ri][0]);
        const float4 rv1 = *reinterpret_cast<const float4*>(&s_ray[ri][4]);
        const float nr = rv1.z, step = rv1.w;
        const float zs = __fadd_rn(nr, __fmul_rn((float)s, step));
        const float zj = zs + jitter[blk * SPB + id] * step;
        const float qx = rv0.x + zj * rv0.w;
        const float qy = rv0.y + zj * rv1.x;
        const float qz = rv0.z + zj * rv1.y;

        // ---- L1: A = [pts | 1.0] (k=0..3 on quad 0); bias rides W1 row 3 ----
        bf16x8 ah = {0, 0, 0, 0, 0, 0, 0, 0};
        if (quad == 0) {
            ah[0] = f2bf(qx); ah[1] = f2bf(qy); ah[2] = f2bf(qz);
            ah[3] = (short)0x3F80;       // bf16(1.0)
        }
        #pragma unroll
        for (int nt = 0; nt < 4; ++nt) {
            const f32x4 c1 = MFMA16(ah, w1f[nt], z4);
            #pragma unroll
            for (int rg = 0; rg < 4; ++rg) {
                hwr[rg * 72 + 16 * nt] = f2bf(fmaxf(c1[rg], 0.0f));
            }
        }

        // ---- L2: h2 = relu(h1) @ W2 + b2 (per-wave scratch, WAR-safe) ----
        const bf16x8 a2_0 = *(const bf16x8*)(hrd);
        const bf16x8 a2_1 = *(const bf16x8*)(hrd + 32);
        #pragma unroll
        for (int nt = 0; nt < 4; ++nt) {
            const f32x4 c2 = MFMA16(a2_1, w2f[nt][1], MFMA16(a2_0, w2f[nt][0], z4));
            #pragma unroll
            for (int rg = 0; rg < 4; ++rg) {
                hwr[rg * 72 + 16 * nt] = f2bf(fmaxf(c2[rg] + b2v[nt], 0.0f));
            }
        }

        // ---- L3 (swapped): D = W3^T @ relu(h2); C cols=samples, rows=channels
        const bf16x8 b3_0 = *(const bf16x8*)(hrd);
        const bf16x8 b3_1 = *(const bf16x8*)(hrd + 32);
        const f32x4 c3 = MFMA16(a3f[1], b3_1, MFMA16(a3f[0], b3_0, z4));

        if (quad == 0 && valid) {
            const float sg = c3[0] + bsg;
            const float tau = fmaxf(sg, 0.0f) * step;
            s_alpha[id] = 1.0f - __expf(-tau);
            s_r[id] = __builtin_amdgcn_rcpf(1.0f + __expf(-(c3[1] + br0)));
            s_g[id] = __builtin_amdgcn_rcpf(1.0f + __expf(-(c3[2] + br1)));
            s_b[id] = __builtin_amdgcn_rcpf(1.0f + __expf(-(c3[3] + br2)));
        }
    }
    __syncthreads();

    // ================= Phase C: composite (2 rays per wave) =================
    #pragma unroll
    for (int ri = wv; ri < RPB; ri += 4) {
        const int gr = blk * RPB + ri;
        if (gr >= N) break;
        const int b0 = ri * S + 2 * lane;
        const float2 a01 = *reinterpret_cast<const float2*>(&s_alpha[b0]);
        const float a0 = a01.x, a1 = a01.y;
        const float t0 = (1.0f - a0) + 1e-10f;
        const float t1 = (1.0f - a1) + 1e-10f;
        float v = t0 * t1;
        #pragma unroll
        for (int off = 1; off < 64; off <<= 1) {
            const float u = __shfl_up(v, off, 64);
            if (lane >= off) v *= u;
        }
        float excl = __shfl_up(v, 1, 64);
        if (lane == 0) excl = 1.0f;
        const float no_hit = __shfl(v, 63, 64);
        const float w0 = a0 * excl;
        const float w1 = a1 * (excl * t0);
        const float2 r01 = *reinterpret_cast<const float2*>(&s_r[b0]);
        const float2 g01 = *reinterpret_cast<const float2*>(&s_g[b0]);
        const float2 b01 = *reinterpret_cast<const float2*>(&s_b[b0]);
        float cr = w0 * r01.x + w1 * r01.y;
        float cg = w0 * g01.x + w1 * g01.y;
        float cb = w0 * b01.x + w1 * b01.y;
        #pragma unroll
        for (int off = 32; off >= 1; off >>= 1) {
            cr += __shfl_xor(cr, off, 64);
            cg += __shfl_xor(cg, off, 64);
            cb += __shfl_xor(cb, off, 64);
        }
        if (lane == 0) {
            out[gr * 3 + 0] = cr + no_hit;
            out[gr * 3 + 1] = cg + no_hit;
            out[gr * 3 + 2] = cb + no_hit;
        }
    }
}

extern "C" void kernel_launch(void* const* d_in, const int* in_sizes, int n_in,
                              void* d_out, int out_size, void* d_ws, size_t ws_size,
                              hipStream_t stream) {
    const float* rays_o  = (const float*)d_in[0];
    const float* rays_d  = (const float*)d_in[1];
    const float* nearv   = (const float*)d_in[2];
    const float* farv    = (const float*)d_in[3];
    const float* jitter  = (const float*)d_in[4];
    const float* density = (const float*)d_in[5];
    const float* W1      = (const float*)d_in[6];
    const float* b1      = (const float*)d_in[7];
    const float* W2      = (const float*)d_in[8];
    const float* b2      = (const float*)d_in[9];
    const float* Wsig    = (const float*)d_in[10];
    const float* bsig    = (const float*)d_in[11];
    const float* Wrgb    = (const float*)d_in[12];
    const float* brgb    = (const float*)d_in[13];
    float* out = (float*)d_out;

    const int N = in_sizes[2];

    fused_mfma_kernel<<<dim3((N + RPB - 1) / RPB), dim3(T), 0, stream>>>(
        rays_o, rays_d, nearv, farv, jitter, density,
        W1, b1, W2, b2, Wsig, bsig, Wrgb, brgb, out, N);
}

// Round 2
// 100.259 us; speedup vs baseline: 1.0548x; 1.0218x over previous
//
#include <hip/hip_runtime.h>
#include <math.h>

#define S 128
#define H 64
#define RPB 8            // rays per block
#define SPB (RPB * S)    // 1024 samples per block
#define T 256

typedef __attribute__((ext_vector_type(8))) short bf16x8;
typedef __attribute__((ext_vector_type(4))) short short4s;
typedef __attribute__((ext_vector_type(4))) float f32x4;
typedef __attribute__((ext_vector_type(2))) unsigned int u32x2;
#define MFMA16(a, b, c) __builtin_amdgcn_mfma_f32_16x16x32_bf16((a), (b), (c), 0, 0, 0)

// RNE float->bf16: native cast (compiler packs adjacent casts into
// v_cvt_pk_bf16_f32; do NOT hand-write cvt_pk asm, m240)
__device__ __forceinline__ short f2bf(float x) {
    __bf16 b = (__bf16)x;
    return __builtin_bit_cast(short, b);
}

// generic pointer to a __shared__ object: low 32 bits = LDS byte offset
__device__ __forceinline__ unsigned lds_off(const void* p) {
    return (unsigned)(size_t)p;
}

union frag_u { bf16x8 v; u32x2 d[2]; };

// Load one K=64 operand (2x bf16x8 frags) from the transposed h image
// hT[64 k][16 samples] via 4x ds_read_b64_tr_b16.
// tr_b16 semantics (m156/m162): for vaddr v, elem j reads byte
//   (v & ~127) + (v & 127)/4 + 32*j
// With v = base + 8*(lane&15) + 256*quad (base 128-aligned):
//   elem j -> element (lane&15) + 16*(8*quad + j)  == h[sample=lane&15][k=8q+j]
// offset:128 -> +4 k-rows (j=4..7); offset:1024 -> +32 k-rows (ks=1).
// s_waitcnt lives INSIDE the asm: consumers of f0/f1 depend on the whole asm
// block, so MFMA cannot be hoisted past the wait (rule #18 safe).
__device__ __forceinline__ void tr_load_pair(unsigned addr, bf16x8& f0, bf16x8& f1) {
    u32x2 r0, r1, r2, r3;
    asm volatile(
        "ds_read_b64_tr_b16 %0, %4 offset:0\n\t"
        "ds_read_b64_tr_b16 %1, %4 offset:128\n\t"
        "ds_read_b64_tr_b16 %2, %4 offset:1024\n\t"
        "ds_read_b64_tr_b16 %3, %4 offset:1152\n\t"
        "s_waitcnt lgkmcnt(0)"
        : "=v"(r0), "=v"(r1), "=v"(r2), "=v"(r3)
        : "v"(addr) : "memory");
    frag_u u0; u0.d[0] = r0; u0.d[1] = r1; f0 = u0.v;
    frag_u u1; u1.d[0] = r2; u1.d[1] = r3; f1 = u1.v;
}

// ---------------------------------------------------------------------------
// Exact-geometry occupancy mask (identical op sequence since round 0;
// _rn intrinsics forbid fma contraction so floor() cells bit-match numpy).
// ---------------------------------------------------------------------------
__device__ __forceinline__ bool sample_mask(
    float ox, float oy, float oz, float dx, float dy, float dz,
    float nr, float step, int s, const float* __restrict__ density)
{
    const float z  = __fadd_rn(nr, __fmul_rn((float)s, step));
    const float px = __fadd_rn(ox, __fmul_rn(z, dx));
    const float py = __fadd_rn(oy, __fmul_rn(z, dy));
    const float pz = __fadd_rn(oz, __fmul_rn(z, dz));
    const float gx = floorf(__fmul_rn(__fdiv_rn(__fsub_rn(px, -1.25f), 2.5f), 64.0f));
    const float gy = floorf(__fmul_rn(__fdiv_rn(__fsub_rn(py, -1.55f), 2.5f), 64.0f));
    const float gz = floorf(__fmul_rn(__fdiv_rn(__fsub_rn(pz, -1.25f), 2.5f), 64.0f));
    const int ix = (int)gx, iy = (int)gy, iz = (int)gz;
    const bool inb = (ix >= 0) && (ix < 64) && (iy >= 0) && (iy < 64) &&
                     (iz >= 0) && (iz < 64);
    const int cx = min(max(ix, 0), 63);
    const int cy = min(max(iy, 0), 63);
    const int cz = min(max(iz, 0), 63);
    const float dval = density[(cx << 12) | (cy << 6) | cz];
    return inb && (dval > 0.5f);
}

// ---------------------------------------------------------------------------
// Fused kernel, round 11:
//  - h scratch stored TRANSPOSED [64 k][16 samples]: C-regs (4 consecutive
//    samples of one k-row) pack into ONE ds_write_b64 -> stores 16->4 per
//    layer transition; frag loads via ds_read_b64_tr_b16 (HW transpose).
//  - one-task-ahead prefetch of s_list id + jitter (dependent ~400cy chain
//    hidden under the previous task's 14-MFMA MLP).
//  - (r10) native bf16 casts, b1 folded into W1 row 3, per-ray LDS staging,
//    sW2t/s_r/s_g union, fast-math epilogue, launch_bounds(256,5).
// MFMA layouts (16x16x32 bf16, HW-verified m89/m91/m120, round-8 end-to-end):
//   A-frag: lane holds A[m=lane&15][k=8*quad+j]; B-frag: B[k=8*quad+j][n=lane&15]
//   C/D: reg r = C[row=4*quad+r][col=lane&15]
// L3 computed swapped (D = W3^T * relu(h2)): quad-0 lanes hold all 4 output
// channels of their sample -> shuffle-free epilogue.
// ---------------------------------------------------------------------------
__global__ __launch_bounds__(256, 5)
void fused_mfma_kernel(const float* __restrict__ rays_o, const float* __restrict__ rays_d,
                       const float* __restrict__ nearv, const float* __restrict__ farv,
                       const float* __restrict__ jitter, const float* __restrict__ density,
                       const float* __restrict__ W1, const float* __restrict__ b1,
                       const float* __restrict__ W2, const float* __restrict__ b2,
                       const float* __restrict__ Wsig, const float* __restrict__ bsig,
                       const float* __restrict__ Wrgb, const float* __restrict__ brgb,
                       float* __restrict__ out, int N)
{
    // sW2t is only read during the once-per-block fragment build; after that
    // its 9.2 KB is reused for s_r/s_g (writes begin only after sync #3).
    __shared__ __align__(16) union {
        short w2t[H * 72];        // bf16 W2 transposed [n][k], 9216 B
        float rg[2 * SPB];        // s_r | s_g, 8192 B
    } s_u;
    // per-wave transposed h scratch [64 k][16 samples] bf16 = 2 KB/wave.
    // 128-aligned: tr_b16 address decomposition needs 128-aligned bases.
    __shared__ __align__(128) short hT[4][H * 16];
    __shared__ unsigned short s_list[SPB];             // 2 KB
    __shared__ __align__(16) float s_alpha[SPB];       // 4 KB
    __shared__ __align__(16) float s_bv[SPB];          // 4 KB
    __shared__ __align__(16) float s_ray[RPB][8];      // {ox,oy,oz,dx,dy,dz,nr,step}
    __shared__ int s_wcnt[4];
    __shared__ int s_wbase[4];

    short* const sW2t = s_u.w2t;
    float* const s_r  = s_u.rg;
    float* const s_g  = s_u.rg + SPB;
    float* const s_b  = s_bv;

    const int tid  = threadIdx.x;
    const int lane = tid & 63;
    const int wv   = tid >> 6;
    const int blk  = blockIdx.x;
    const int mrow = lane & 15;      // 16-dim index (row for A/C, col for B)
    const int quad = lane >> 4;      // k-quad

    // ---- stage per-ray data (8 rays) ----
    if (tid < RPB) {
        const int gr = blk * RPB + tid;
        float ox = 0.f, oy = 0.f, oz = 0.f, dx = 0.f, dy = 0.f, dz = 0.f,
              nr = 0.f, st = 0.f;
        if (gr < N) {
            ox = rays_o[gr * 3 + 0]; oy = rays_o[gr * 3 + 1]; oz = rays_o[gr * 3 + 2];
            dx = rays_d[gr * 3 + 0]; dy = rays_d[gr * 3 + 1]; dz = rays_d[gr * 3 + 2];
            nr = nearv[gr];
            st = __fdiv_rn(__fsub_rn(farv[gr], nr), 128.0f);
        }
        s_ray[tid][0] = ox; s_ray[tid][1] = oy; s_ray[tid][2] = oz; s_ray[tid][3] = dx;
        s_ray[tid][4] = dy; s_ray[tid][5] = dz; s_ray[tid][6] = nr; s_ray[tid][7] = st;
    }
    // ---- stage W2 bf16 TRANSPOSED into LDS (coalesced global reads) ----
    for (int e = tid; e < H * H; e += T) {
        const int k = e >> 6, n = e & 63;
        sW2t[n * 72 + k] = f2bf(W2[e]);
    }
    __syncthreads();   // sync 1: s_ray + sW2t visible

    // ================= Phase A: mask (registers only) =======================
    const int lbase = tid * 4;            // local sample ids lbase..lbase+3
    const int rloc  = lbase >> 7;         // local ray 0..7
    const int gra   = blk * RPB + rloc;
    unsigned int mybits = 0u;
    {
        const float4 rv0 = *reinterpret_cast<const float4*>(&s_ray[rloc][0]);
        const float4 rv1 = *reinterpret_cast<const float4*>(&s_ray[rloc][4]);
        if (gra < N) {
            const int s0 = lbase & (S - 1);
            #pragma unroll
            for (int j = 0; j < 4; ++j) {
                if (sample_mask(rv0.x, rv0.y, rv0.z, rv0.w, rv1.x, rv1.y,
                                rv1.z, rv1.w, s0 + j, density))
                    mybits |= (1u << j);
            }
        }
    }
    const int mycnt = __popc(mybits);
    int inc = mycnt;
    #pragma unroll
    for (int off = 1; off < 64; off <<= 1) {
        const int u = __shfl_up(inc, off, 64);
        if (lane >= off) inc += u;
    }
    if (lane == 63) s_wcnt[wv] = inc;

    // ================= Weight fragments (once per block) ====================
    // Built here, between sync 1 and sync 3, so sW2t can be reused afterwards.
    bf16x8 w2f[4][2];
    #pragma unroll
    for (int nt = 0; nt < 4; ++nt) {
        #pragma unroll
        for (int ks = 0; ks < 2; ++ks) {
            w2f[nt][ks] = *(const bf16x8*)&sW2t[(mrow + 16 * nt) * 72 + 32 * ks + 8 * quad];
        }
    }
    // W1 B-frags: rows k=0..2 = input dims, row k=3 = b1 (A supplies 1.0)
    bf16x8 w1f[4];
    #pragma unroll
    for (int nt = 0; nt < 4; ++nt) {
        bf16x8 f = {0, 0, 0, 0, 0, 0, 0, 0};
        if (quad == 0) {
            const int n = mrow + 16 * nt;
            f[0] = f2bf(W1[n]);
            f[1] = f2bf(W1[64 + n]);
            f[2] = f2bf(W1[128 + n]);
            f[3] = f2bf(b1[n]);          // bias row (exact: b1 == 0 here)
        }
        w1f[nt] = f;
    }
    // L3 A-frags: A[m=channel][k]; ch0=Wsig, ch1..3=Wrgb
    bf16x8 a3f[2];
    #pragma unroll
    for (int ks = 0; ks < 2; ++ks) {
        bf16x8 f = {0, 0, 0, 0, 0, 0, 0, 0};
        if (mrow < 4) {
            #pragma unroll
            for (int j = 0; j < 8; ++j) {
                const int k = 32 * ks + 8 * quad + j;
                const float v = (mrow == 0) ? Wsig[k] : Wrgb[k * 3 + (mrow - 1)];
                f[j] = f2bf(v);
            }
        }
        a3f[ks] = f;
    }
    float b2v[4];
    #pragma unroll
    for (int nt = 0; nt < 4; ++nt) b2v[nt] = b2[mrow + 16 * nt];
    const float bsg = bsig[0];
    const float br0 = brgb[0], br1 = brgb[1], br2 = brgb[2];

    __syncthreads();   // sync 2: s_wcnt visible; all sW2t reads complete
    if (tid == 0) {
        int t0 = 0;
        #pragma unroll
        for (int i = 0; i < 4; ++i) { s_wbase[i] = t0; t0 += s_wcnt[i]; }
    }
    __syncthreads();   // sync 3: s_wbase visible; safe to clobber sW2t region
    int pos = s_wbase[wv] + (inc - mycnt);
    #pragma unroll
    for (int j = 0; j < 4; ++j) {
        if ((mybits >> j) & 1u) {
            s_list[pos++] = (unsigned short)(lbase + j);
        } else {
            s_alpha[lbase + j] = 0.0f;
            s_r[lbase + j] = 0.0f;
            s_g[lbase + j] = 0.0f;
            s_b[lbase + j] = 0.0f;
        }
    }
    const int K = s_wbase[3] + s_wcnt[3];
    __syncthreads();   // sync 4: s_list + zero-fills visible

    // ================= Phase B: MFMA MLP over 16-sample tasks ===============
    const f32x4 z4 = {0.f, 0.f, 0.f, 0.f};
    const int ntask = (K + 15) >> 4;
    short* const hb2 = &hT[wv][0];
    // packed C-store base: element (mrow+16nt)*16 + 4q -> short4s slot + 64*nt
    short4s* const hst = (short4s*)&hb2[mrow * 16 + 4 * quad];
    // tr-read base (see tr_load_pair comment)
    const unsigned trA = lds_off(hb2) + 8 * mrow + 256 * quad;

    // software pipeline: prefetch task t's {id, valid, jitter} one iter ahead
    int nid = 0, nval = 0;
    float njit = 0.0f;
    if (ntask > wv) {
        const int slot = (wv << 4) + mrow;
        nval = slot < K;
        nid = s_list[nval ? slot : 0];
        njit = jitter[blk * SPB + nid];
    }

    for (int t = wv; t < ntask; t += 4) {
        const int id = nid;
        const int valid = nval;
        const float jit = njit;
        const int tn = t + 4;
        if (tn < ntask) {
            const int slot = (tn << 4) + mrow;
            nval = slot < K;
            nid = s_list[nval ? slot : 0];
            njit = jitter[blk * SPB + nid];
        }

        const int ri = id >> 7;
        const int s  = id & (S - 1);
        const float4 rv0 = *reinterpret_cast<const float4*>(&s_ray[ri][0]);
        const float4 rv1 = *reinterpret_cast<const float4*>(&s_ray[ri][4]);
        const float nr = rv1.z, step = rv1.w;
        const float zs = __fadd_rn(nr, __fmul_rn((float)s, step));
        const float zj = zs + jit * step;
        const float qx = rv0.x + zj * rv0.w;
        const float qy = rv0.y + zj * rv1.x;
        const float qz = rv0.z + zj * rv1.y;

        // ---- L1: A = [pts | 1.0] (k=0..3 on quad 0); bias rides W1 row 3 ----
        bf16x8 ah = {0, 0, 0, 0, 0, 0, 0, 0};
        if (quad == 0) {
            ah[0] = f2bf(qx); ah[1] = f2bf(qy); ah[2] = f2bf(qz);
            ah[3] = (short)0x3F80;       // bf16(1.0)
        }
        #pragma unroll
        for (int nt = 0; nt < 4; ++nt) {
            const f32x4 c1 = MFMA16(ah, w1f[nt], z4);
            short4s pk;
            pk[0] = f2bf(fmaxf(c1[0], 0.0f));
            pk[1] = f2bf(fmaxf(c1[1], 0.0f));
            pk[2] = f2bf(fmaxf(c1[2], 0.0f));
            pk[3] = f2bf(fmaxf(c1[3], 0.0f));
            hst[nt * 64] = pk;           // one ds_write_b64 per nt
        }

        // ---- L2: h2 = relu(h1) @ W2 + b2 (tr-reads; WAR-safe: DS in-order
        //      per wave, stores below are ordered after the asm reads) ----
        bf16x8 a2_0, a2_1;
        tr_load_pair(trA, a2_0, a2_1);
        #pragma unroll
        for (int nt = 0; nt < 4; ++nt) {
            const f32x4 c2 = MFMA16(a2_1, w2f[nt][1], MFMA16(a2_0, w2f[nt][0], z4));
            short4s pk;
            pk[0] = f2bf(fmaxf(c2[0] + b2v[nt], 0.0f));
            pk[1] = f2bf(fmaxf(c2[1] + b2v[nt], 0.0f));
            pk[2] = f2bf(fmaxf(c2[2] + b2v[nt], 0.0f));
            pk[3] = f2bf(fmaxf(c2[3] + b2v[nt], 0.0f));
            hst[nt * 64] = pk;
        }

        // ---- L3 (swapped): D = W3^T @ relu(h2); C cols=samples, rows=channels
        bf16x8 b3_0, b3_1;
        tr_load_pair(trA, b3_0, b3_1);
        const f32x4 c3 = MFMA16(a3f[1], b3_1, MFMA16(a3f[0], b3_0, z4));

        if (quad == 0 && valid) {
            const float sg = c3[0] + bsg;
            const float tau = fmaxf(sg, 0.0f) * step;
            s_alpha[id] = 1.0f - __expf(-tau);
            s_r[id] = __builtin_amdgcn_rcpf(1.0f + __expf(-(c3[1] + br0)));
            s_g[id] = __builtin_amdgcn_rcpf(1.0f + __expf(-(c3[2] + br1)));
            s_b[id] = __builtin_amdgcn_rcpf(1.0f + __expf(-(c3[3] + br2)));
        }
    }
    __syncthreads();

    // ================= Phase C: composite (2 rays per wave) =================
    #pragma unroll
    for (int ri = wv; ri < RPB; ri += 4) {
        const int gr = blk * RPB + ri;
        if (gr >= N) break;
        const int b0 = ri * S + 2 * lane;
        const float2 a01 = *reinterpret_cast<const float2*>(&s_alpha[b0]);
        const float a0 = a01.x, a1 = a01.y;
        const float t0 = (1.0f - a0) + 1e-10f;
        const float t1 = (1.0f - a1) + 1e-10f;
        float v = t0 * t1;
        #pragma unroll
        for (int off = 1; off < 64; off <<= 1) {
            const float u = __shfl_up(v, off, 64);
            if (lane >= off) v *= u;
        }
        float excl = __shfl_up(v, 1, 64);
        if (lane == 0) excl = 1.0f;
        const float no_hit = __shfl(v, 63, 64);
        const float w0 = a0 * excl;
        const float w1 = a1 * (excl * t0);
        const float2 r01 = *reinterpret_cast<const float2*>(&s_r[b0]);
        const float2 g01 = *reinterpret_cast<const float2*>(&s_g[b0]);
        const float2 b01 = *reinterpret_cast<const float2*>(&s_b[b0]);
        float cr = w0 * r01.x + w1 * r01.y;
        float cg = w0 * g01.x + w1 * g01.y;
        float cb = w0 * b01.x + w1 * b01.y;
        #pragma unroll
        for (int off = 32; off >= 1; off >>= 1) {
            cr += __shfl_xor(cr, off, 64);
            cg += __shfl_xor(cg, off, 64);
            cb += __shfl_xor(cb, off, 64);
        }
        if (lane == 0) {
            out[gr * 3 + 0] = cr + no_hit;
            out[gr * 3 + 1] = cg + no_hit;
            out[gr * 3 + 2] = cb + no_hit;
        }
    }
}

extern "C" void kernel_launch(void* const* d_in, const int* in_sizes, int n_in,
                              void* d_out, int out_size, void* d_ws, size_t ws_size,
                              hipStream_t stream) {
    const float* rays_o  = (const float*)d_in[0];
    const float* rays_d  = (const float*)d_in[1];
    const float* nearv   = (const float*)d_in[2];
    const float* farv    = (const float*)d_in[3];
    const float* jitter  = (const float*)d_in[4];
    const float* density = (const float*)d_in[5];
    const float* W1      = (const float*)d_in[6];
    const float* b1      = (const float*)d_in[7];
    const float* W2      = (const float*)d_in[8];
    const float* b2      = (const float*)d_in[9];
    const float* Wsig    = (const float*)d_in[10];
    const float* bsig    = (const float*)d_in[11];
    const float* Wrgb    = (const float*)d_in[12];
    const float* brgb    = (const float*)d_in[13];
    float* out = (float*)d_out;

    const int N = in_sizes[2];

    fused_mfma_kernel<<<dim3((N + RPB - 1) / RPB), dim3(T), 0, stream>>>(
        rays_o, rays_d, nearv, farv, jitter, density,
        W1, b1, W2, b2, Wsig, bsig, Wrgb, brgb, out, N);
}